// Round 6
// baseline (7131.638 us; speedup 1.0000x reference)
//
#include <hip/hip_runtime.h>

typedef __attribute__((ext_vector_type(8))) short short8;
typedef __attribute__((ext_vector_type(4))) float f32x4;

#define NN 4096     // neurons
#define NB 32       // batch
#define TSTEPS 291  // t = 0..290 (last record at t=290; steps 291..299 unused)
#define FF_T 300    // ff_input time stride
#define NBLK 256    // grid size == CU count; 1 block/CU capacity guaranteed
#define FSTR 64     // flag stride in ints (256B per flag -> own cache line)

// ============================================================================
// ABLATION ROUND (R6): identical to R5 except the end-of-step grid_barrier is
// executed TWICE back-to-back. The second barrier is semantically idempotent
// (no stores between the two), so the measured delta vs R5 = 291 x C2 where
// C2 is the pure sync-primitive cost (flag-store visibility + all-to-all
// detect + 2 syncthreads + buffer_inv) with no drain and no skew. This
// decomposes R5's 15.7us/step into sync-primitive vs skew/drain/datapath.
// ============================================================================

// float -> bf16 round-to-nearest-even, raw bits in a short
__device__ __forceinline__ short f2bf(float x) {
    unsigned u = __builtin_bit_cast(unsigned, x);
    unsigned r = (u + 0x7FFFu + ((u >> 16) & 1u)) >> 16;
    return (short)r;
}
__device__ __forceinline__ unsigned pack2bf(float x0, float x1) {
    return ((unsigned)(unsigned short)f2bf(x0))
         | (((unsigned)(unsigned short)f2bf(x1)) << 16);
}

// Coherent-point store/load (global_store/load_dword sc1 — bypass L2,
// visible cross-XCD without any fence). R4 proved cached stores + per-step
// agent release fence (buffer_wbl2) cost +14us/step with identical HBM
// traffic — sc1 stores are the right publish path on this chip.
__device__ __forceinline__ void st_coh(int* p, int v) {
    __hip_atomic_store(p, v, __ATOMIC_RELAXED, __HIP_MEMORY_SCOPE_AGENT);
}
__device__ __forceinline__ int ld_coh(const int* p) {
    return __hip_atomic_load(p, __ATOMIC_RELAXED, __HIP_MEMORY_SCOPE_AGENT);
}

// rates fragment layout (units: shorts): [k>>5][m>>4][(k>>3)&3][m&15][k&7]
// Exactly the 16x16x32 MFMA A-fragment lane order (verified R1/R2/R5).
// Consumer wave reads contiguous 1KB chunks; producer publishes exactly one
// packed dword per thread.
__device__ __forceinline__ int foff(int m, int k) {
    return ((k >> 5) << 10) | ((m >> 4) << 9) | (((k >> 3) & 3) << 7)
         | ((m & 15) << 3) | (k & 7);
}

// One-hop all-to-all grid barrier with 256B-padded flags (R5-proven).
// Arrival = one plain sc1 store to the block's own flag line; completion =
// thread i polls flag i directly. One acquire fence (buffer_inv) per call.
__device__ __forceinline__ void grid_barrier(int* __restrict__ flags, int epoch) {
    __syncthreads();   // all waves: s_waitcnt vmcnt(0) — prior stores ordered
    if (threadIdx.x == 0)
        st_coh(&flags[(size_t)blockIdx.x * FSTR], epoch);
    while (ld_coh(&flags[(size_t)threadIdx.x * FSTR]) < epoch)
        __builtin_amdgcn_s_sleep(2);
    __syncthreads();
    __builtin_amdgcn_fence(__ATOMIC_ACQUIRE, "agent");  // buffer_inv only
}

// Persistent kernel. One WG per CU; WG c owns output columns [16c,16c+16)
// for all 32 batches. W lives in registers as MFMA B-frags (128 VGPRs/wave)
// for the whole run. Per-neuron fp32 state (rec, rate, window-acc) in
// registers: thread owns elements (b = tid>>3, n = n0 + (tid&7)*2 + {0,1}).
__global__ __launch_bounds__(256, 1)
void rnn_kernel(const float* __restrict__ W,
                const float* __restrict__ ff,
                const float* __restrict__ rec0p,
                float* __restrict__ out,
                int* __restrict__ flags,
                short* __restrict__ ratesA,
                short* __restrict__ ratesB)
{
    const int tid  = threadIdx.x;
    const int wave = tid >> 6;
    const int lane = tid & 63;
    const int n0   = blockIdx.x * 16;

    __shared__ float part[4][32][18];   // per-wave K-partials (padded)

    // per-thread state element indices
    const int sb  = tid >> 3;           // batch 0..31
    const int nl0 = (tid & 7) * 2;      // even neuron-local index 0..14
    const int fo  = foff(sb, n0 + nl0); // fragment dword slot (even)

    // ---- init: rec0, rates0 = relu(ff[:,0] + rec0)
    const size_t sidx = (size_t)sb * NN + n0 + nl0;
    float rc0 = rec0p[sidx], rc1 = rec0p[sidx + 1];
    const float* ff0p = ff + ((size_t)sb * FF_T) * NN + n0 + nl0;
    float rt0 = fmaxf(ff0p[0] + rc0, 0.0f);
    float rt1 = fmaxf(ff0p[1] + rc1, 0.0f);
    float ac0 = 0.0f, ac1 = 0.0f;
    st_coh((int*)(ratesA + fo), (int)pack2bf(rt0, rt1));

    // ---- W (fp32 [k][n]) -> register bf16 B-fragments.
    // wave w covers k in [w*1024, (w+1)*1024); for K-step kt, lane holds
    // B[k = w*1024 + kt*32 + (lane>>4)*8 + j][n = n0 + (lane&15)], j=0..7
    short8 Bfr[32];
    {
        const int ncol  = n0 + (lane & 15);
        const size_t kb = (size_t)(wave * 1024 + ((lane >> 4) * 8));
        #pragma unroll
        for (int kt = 0; kt < 32; ++kt) {
            short8 f;
            #pragma unroll
            for (int j = 0; j < 8; ++j) {
                f[j] = f2bf(W[(kb + (size_t)kt * 32 + j) * NN + ncol]);
            }
            Bfr[kt] = f;
        }
    }

    int epoch = 1;
    grid_barrier(flags, epoch);   // rates0 globally visible

    // A-loads: contiguous fragment stream. Wave w owns shorts
    // [w*32768, (w+1)*32768); per kt two 1KB coalesced chunks
    // (m-tiles 0/1 at +0 / +512 shorts).
    const int wl = (wave << 15) + (lane << 3);

    for (int t = 0; t < TSTEPS; ++t) {
        const short* __restrict__ rbuf = (t & 1) ? ratesB : ratesA;
        short* __restrict__ wbuf       = (t & 1) ? ratesA : ratesB;

        // this step's ff: issued at top of step, consumed after the MFMA
        // loop — HBM latency overlaps the MFMA chain
        const float* ffp = ff + ((size_t)sb * FF_T + t) * NN + n0 + nl0;
        const float ffv0 = ffp[0];
        const float ffv1 = ffp[1];

        f32x4 acc0 = {0.f, 0.f, 0.f, 0.f};
        f32x4 acc1 = {0.f, 0.f, 0.f, 0.f};
        const short* pw = rbuf + wl;
        #pragma unroll
        for (int kt = 0; kt < 32; ++kt) {
            short8 a0 = *(const short8*)(pw + (kt << 10));
            short8 a1 = *(const short8*)(pw + (kt << 10) + 512);
            acc0 = __builtin_amdgcn_mfma_f32_16x16x32_bf16(a0, Bfr[kt], acc0, 0, 0, 0);
            acc1 = __builtin_amdgcn_mfma_f32_16x16x32_bf16(a1, Bfr[kt], acc1, 0, 0, 0);
        }

        // C/D layout: col = lane&15, row = (lane>>4)*4 + reg  [m89-verified]
        const int prow = (lane >> 4) * 4;
        const int pcol = lane & 15;
        #pragma unroll
        for (int r = 0; r < 4; ++r) {
            part[wave][prow + r][pcol]      = acc0[r];
            part[wave][16 + prow + r][pcol] = acc1[r];
        }
        __syncthreads();

        // fused update on this thread's two elements (state in registers)
        const float h0 = part[0][sb][nl0] + part[1][sb][nl0]
                       + part[2][sb][nl0] + part[3][sb][nl0];
        const float h1 = part[0][sb][nl0+1] + part[1][sb][nl0+1]
                       + part[2][sb][nl0+1] + part[3][sb][nl0+1];
        rc0 = rc0 * 0.95122945f + h0 * 0.05f;   // exp(-dt/tau_syn), dt/tau_syn
        rc1 = rc1 * 0.95122945f + h1 * 0.05f;
        rt0 = rt0 * 0.90483743f + fmaxf(ffv0 + rc0, 0.0f) * 0.1f; // exp(-dt/tau), dt/tau
        rt1 = rt1 * 0.90483743f + fmaxf(ffv1 + rc1, 0.0f) * 0.1f;
        if (t >= 90) { ac0 += rt0; ac1 += rt1; }
        // publish new rates straight to the coherence point (sc1 store,
        // fragment layout — exactly one dword per thread)
        st_coh((int*)(wbuf + fo), (int)pack2bf(rt0, rt1));

        // record: windows end at t = 100,110,...,290 (first window = 11 terms
        // /10, matching cs[100]-cs[89] in the reference)
        if (t >= 100 && (t % 10) == 0) {
            const int w = (t - 100) / 10;
            float* op = out + ((size_t)sb * 20 + w) * NN + n0 + nl0;
            op[0] = ac0 * 0.1f;
            op[1] = ac1 * 0.1f;
            ac0 = 0.0f; ac1 = 0.0f;
        }

        // ---- barrier 1 (functional): publishes new rates, orders buffers
        epoch++;
        grid_barrier(flags, epoch);
        // ---- barrier 2 (ABLATION probe): idempotent — zero new stores to
        // drain, near-zero skew. Its marginal cost == pure sync primitive.
        epoch++;
        grid_barrier(flags, epoch);
    }
}

extern "C" void kernel_launch(void* const* d_in, const int* in_sizes, int n_in,
                              void* d_out, int out_size, void* d_ws, size_t ws_size,
                              hipStream_t stream)
{
    const float* W    = (const float*)d_in[0];   // Wab_T [4096,4096] fp32, row-major [k][n]
    const float* ff   = (const float*)d_in[1];   // [32,300,4096] fp32
    const float* rec0 = (const float*)d_in[2];   // [32,4096] fp32
    float* out = (float*)d_out;                  // [32,20,4096] fp32

    int*   flags  = (int*)d_ws;                    // 256 flags, 256B apart (64KB)
    short* ratesA = (short*)((char*)d_ws + 65536); // bf16 rates double buffer
    short* ratesB = ratesA + NB * NN;

    hipMemsetAsync(d_ws, 0, 65536, stream);        // graph-capturable memset node

    rnn_kernel<<<dim3(NBLK), dim3(256), 0, stream>>>(W, ff, rec0, out,
                                                     flags, ratesA, ratesB);
}

// Round 7
// 5199.352 us; speedup vs baseline: 1.3716x; 1.3716x over previous
//
#include <hip/hip_runtime.h>

typedef __attribute__((ext_vector_type(8))) short short8;
typedef __attribute__((ext_vector_type(4))) float f32x4;

#define NN 4096     // neurons
#define NB 32       // batch
#define TSTEPS 291  // t = 0..290 (last record at t=290; steps 291..299 unused)
#define FF_T 300    // ff_input time stride
#define NBLK 256    // grid size == CU count; 1 block/CU capacity guaranteed

// float -> bf16 round-to-nearest-even, raw bits in a short
__device__ __forceinline__ short f2bf(float x) {
    unsigned u = __builtin_bit_cast(unsigned, x);
    unsigned r = (u + 0x7FFFu + ((u >> 16) & 1u)) >> 16;
    return (short)r;
}
__device__ __forceinline__ unsigned pack2bf(float x0, float x1) {
    return ((unsigned)(unsigned short)f2bf(x0))
         | (((unsigned)(unsigned short)f2bf(x1)) << 16);
}

// Coherent-point store/load (global_store/load_dword sc1 — bypass L2,
// visible cross-XCD without any fence). R4 proved cached stores + per-step
// agent release fence (buffer_wbl2) cost +14us/step with identical HBM
// traffic — sc1 stores are the right publish path on this chip.
__device__ __forceinline__ void st_coh(int* p, int v) {
    __hip_atomic_store(p, v, __ATOMIC_RELAXED, __HIP_MEMORY_SCOPE_AGENT);
}
__device__ __forceinline__ int ld_coh(const int* p) {
    return __hip_atomic_load(p, __ATOMIC_RELAXED, __HIP_MEMORY_SCOPE_AGENT);
}

// rates fragment layout (units: shorts): [k>>5][m>>4][(k>>3)&3][m&15][k&7]
// Exactly the 16x16x32 MFMA A-fragment lane order (verified R1/R2/R5).
// Consumer wave reads contiguous 1KB chunks; producer publishes exactly one
// packed dword per thread.
__device__ __forceinline__ int foff(int m, int k) {
    return ((k >> 5) << 10) | ((m >> 4) << 9) | (((k >> 3) & 3) << 7)
         | ((m & 15) << 3) | (k & 7);
}

// One-hop all-to-all grid barrier, COALESCED polling (R6 ablation fix).
// R6 measured the R5 primitive at 8.2us/call with zero skew/drain; its
// padded-flag poll made each wave's poll instruction touch 64 DISTINCT
// cache lines (65,536 line requests per round chip-wide) and pushed
// ~39MB/barrier of poll traffic to HBM. Fix:
//   - flags packed at 4B stride (256 flags = 8 lines total)
//   - only wave 0 polls: lane l checks flags[l], [64+l], [128+l], [192+l]
//     -> four fully-coalesced wave-loads = 8 line requests per block per
//     round (32x fewer chip-wide); waves 1-3 wait at __syncthreads
// Arrival stays one plain sc1 dword store to the block's own flag (no RMW
// — R1's atomicAdd serialized the critical word; dword writes to shared
// lines serialize in ns at the L3 slice, proven harmless by R0's go word).
// __syncthreads before arrival drains each wave's vmcnt, so flag
// visibility implies rates visibility. One acquire fence (buffer_inv) per
// block per step keeps normal cached A-loads correct while preserving
// per-XCD L2 broadcast amplification.
__device__ __forceinline__ void grid_barrier(int* __restrict__ flags, int epoch) {
    __syncthreads();   // all waves: s_waitcnt vmcnt(0) — rates stores ordered
    if (threadIdx.x == 0)
        st_coh(&flags[blockIdx.x], epoch);
    if (threadIdx.x < 64) {          // wave 0 only
        for (;;) {
            const int a = ld_coh(&flags[threadIdx.x]);
            const int b = ld_coh(&flags[64  + threadIdx.x]);
            const int c = ld_coh(&flags[128 + threadIdx.x]);
            const int d = ld_coh(&flags[192 + threadIdx.x]);
            const int m = min(min(a, b), min(c, d));
            if (__all(m >= epoch)) break;
            __builtin_amdgcn_s_sleep(1);
        }
    }
    __syncthreads();
    __builtin_amdgcn_fence(__ATOMIC_ACQUIRE, "agent");  // buffer_inv only
}

// Persistent kernel. One WG per CU; WG c owns output columns [16c,16c+16)
// for all 32 batches. W lives in registers as MFMA B-frags (128 VGPRs/wave)
// for the whole run. Per-neuron fp32 state (rec, rate, window-acc) in
// registers: thread owns elements (b = tid>>3, n = n0 + (tid&7)*2 + {0,1}).
__global__ __launch_bounds__(256, 1)
void rnn_kernel(const float* __restrict__ W,
                const float* __restrict__ ff,
                const float* __restrict__ rec0p,
                float* __restrict__ out,
                int* __restrict__ flags,
                short* __restrict__ ratesA,
                short* __restrict__ ratesB)
{
    const int tid  = threadIdx.x;
    const int wave = tid >> 6;
    const int lane = tid & 63;
    const int n0   = blockIdx.x * 16;

    __shared__ float part[4][32][18];   // per-wave K-partials (padded)

    // per-thread state element indices
    const int sb  = tid >> 3;           // batch 0..31
    const int nl0 = (tid & 7) * 2;      // even neuron-local index 0..14
    const int fo  = foff(sb, n0 + nl0); // fragment dword slot (even)

    // ---- init: rec0, rates0 = relu(ff[:,0] + rec0)
    const size_t sidx = (size_t)sb * NN + n0 + nl0;
    float rc0 = rec0p[sidx], rc1 = rec0p[sidx + 1];
    const float* ff0p = ff + ((size_t)sb * FF_T) * NN + n0 + nl0;
    float rt0 = fmaxf(ff0p[0] + rc0, 0.0f);
    float rt1 = fmaxf(ff0p[1] + rc1, 0.0f);
    float ac0 = 0.0f, ac1 = 0.0f;
    st_coh((int*)(ratesA + fo), (int)pack2bf(rt0, rt1));

    // ---- W (fp32 [k][n]) -> register bf16 B-fragments.
    // wave w covers k in [w*1024, (w+1)*1024); for K-step kt, lane holds
    // B[k = w*1024 + kt*32 + (lane>>4)*8 + j][n = n0 + (lane&15)], j=0..7
    short8 Bfr[32];
    {
        const int ncol  = n0 + (lane & 15);
        const size_t kb = (size_t)(wave * 1024 + ((lane >> 4) * 8));
        #pragma unroll
        for (int kt = 0; kt < 32; ++kt) {
            short8 f;
            #pragma unroll
            for (int j = 0; j < 8; ++j) {
                f[j] = f2bf(W[(kb + (size_t)kt * 32 + j) * NN + ncol]);
            }
            Bfr[kt] = f;
        }
    }

    int epoch = 1;
    grid_barrier(flags, epoch);   // rates0 globally visible

    // A-loads: contiguous fragment stream. Wave w owns shorts
    // [w*32768, (w+1)*32768); per kt two 1KB coalesced chunks
    // (m-tiles 0/1 at +0 / +512 shorts).
    const int wl = (wave << 15) + (lane << 3);

    for (int t = 0; t < TSTEPS; ++t) {
        const short* __restrict__ rbuf = (t & 1) ? ratesB : ratesA;
        short* __restrict__ wbuf       = (t & 1) ? ratesA : ratesB;

        // this step's ff: issued at top of step, consumed after the MFMA
        // loop — HBM latency overlaps the MFMA chain
        const float* ffp = ff + ((size_t)sb * FF_T + t) * NN + n0 + nl0;
        const float ffv0 = ffp[0];
        const float ffv1 = ffp[1];

        f32x4 acc0 = {0.f, 0.f, 0.f, 0.f};
        f32x4 acc1 = {0.f, 0.f, 0.f, 0.f};
        const short* pw = rbuf + wl;
        #pragma unroll
        for (int kt = 0; kt < 32; ++kt) {
            short8 a0 = *(const short8*)(pw + (kt << 10));
            short8 a1 = *(const short8*)(pw + (kt << 10) + 512);
            acc0 = __builtin_amdgcn_mfma_f32_16x16x32_bf16(a0, Bfr[kt], acc0, 0, 0, 0);
            acc1 = __builtin_amdgcn_mfma_f32_16x16x32_bf16(a1, Bfr[kt], acc1, 0, 0, 0);
        }

        // C/D layout: col = lane&15, row = (lane>>4)*4 + reg  [m89-verified]
        const int prow = (lane >> 4) * 4;
        const int pcol = lane & 15;
        #pragma unroll
        for (int r = 0; r < 4; ++r) {
            part[wave][prow + r][pcol]      = acc0[r];
            part[wave][16 + prow + r][pcol] = acc1[r];
        }
        __syncthreads();

        // fused update on this thread's two elements (state in registers)
        const float h0 = part[0][sb][nl0] + part[1][sb][nl0]
                       + part[2][sb][nl0] + part[3][sb][nl0];
        const float h1 = part[0][sb][nl0+1] + part[1][sb][nl0+1]
                       + part[2][sb][nl0+1] + part[3][sb][nl0+1];
        rc0 = rc0 * 0.95122945f + h0 * 0.05f;   // exp(-dt/tau_syn), dt/tau_syn
        rc1 = rc1 * 0.95122945f + h1 * 0.05f;
        rt0 = rt0 * 0.90483743f + fmaxf(ffv0 + rc0, 0.0f) * 0.1f; // exp(-dt/tau), dt/tau
        rt1 = rt1 * 0.90483743f + fmaxf(ffv1 + rc1, 0.0f) * 0.1f;
        if (t >= 90) { ac0 += rt0; ac1 += rt1; }
        // publish new rates straight to the coherence point (sc1 store,
        // fragment layout — exactly one dword per thread)
        st_coh((int*)(wbuf + fo), (int)pack2bf(rt0, rt1));

        // record: windows end at t = 100,110,...,290 (first window = 11 terms
        // /10, matching cs[100]-cs[89] in the reference)
        if (t >= 100 && (t % 10) == 0) {
            const int w = (t - 100) / 10;
            float* op = out + ((size_t)sb * 20 + w) * NN + n0 + nl0;
            op[0] = ac0 * 0.1f;
            op[1] = ac1 * 0.1f;
            ac0 = 0.0f; ac1 = 0.0f;
        }

        epoch++;
        grid_barrier(flags, epoch);  // publishes new rates; orders LDS reuse
    }
}

extern "C" void kernel_launch(void* const* d_in, const int* in_sizes, int n_in,
                              void* d_out, int out_size, void* d_ws, size_t ws_size,
                              hipStream_t stream)
{
    const float* W    = (const float*)d_in[0];   // Wab_T [4096,4096] fp32, row-major [k][n]
    const float* ff   = (const float*)d_in[1];   // [32,300,4096] fp32
    const float* rec0 = (const float*)d_in[2];   // [32,4096] fp32
    float* out = (float*)d_out;                  // [32,20,4096] fp32

    int*   flags  = (int*)d_ws;                   // 256 packed flags (1KB, 8 lines)
    short* ratesA = (short*)((char*)d_ws + 4096); // bf16 rates double buffer
    short* ratesB = ratesA + NB * NN;

    hipMemsetAsync(d_ws, 0, 4096, stream);        // graph-capturable memset node

    rnn_kernel<<<dim3(NBLK), dim3(256), 0, stream>>>(W, ff, rec0, out,
                                                     flags, ratesA, ratesB);
}

// Round 8
// 3209.108 us; speedup vs baseline: 2.2223x; 1.6202x over previous
//
#include <hip/hip_runtime.h>

typedef __attribute__((ext_vector_type(8))) short short8;
typedef __attribute__((ext_vector_type(4))) float f32x4;

#define NN 4096     // neurons
#define NB 32       // batch
#define TSTEPS 291  // t = 0..290 (last record at t=290; steps 291..299 unused)
#define FF_T 300    // ff_input time stride
#define NBLK 256    // grid size == CU count; 1 block/CU capacity guaranteed
#define FSTR 64     // flag stride in ints (256B per flag -> own cache line)
#define RNG (NB * NN)  // shorts per ring buffer (256KB)

// ============================================================================
// R8: R5 (best, 4577us) with ONE isolated change — the per-step agent-acquire
// fence (buffer_inv, full-L2 invalidate walk) is elided to every 4th step via
// a 4-deep rates ring. Buffer b=t%4 is read at t and previously at t-4; the
// single fence in (t-4, t] (at t%4==0, after the barrier) kills any stale
// L1/L2 copy before the re-read. R4 measured the write-side L2 walk (wbl2) at
// +14us/step; this probes whether the read-side walk is the hidden ~3us of
// R6's 8.2us/call barrier primitive. Barrier topology/polling = R5 verbatim.
// ============================================================================

// float -> bf16 round-to-nearest-even, raw bits in a short
__device__ __forceinline__ short f2bf(float x) {
    unsigned u = __builtin_bit_cast(unsigned, x);
    unsigned r = (u + 0x7FFFu + ((u >> 16) & 1u)) >> 16;
    return (short)r;
}
__device__ __forceinline__ unsigned pack2bf(float x0, float x1) {
    return ((unsigned)(unsigned short)f2bf(x0))
         | (((unsigned)(unsigned short)f2bf(x1)) << 16);
}

// Coherent-point store/load (global_store/load_dword sc1 — bypass L2,
// visible cross-XCD without any fence).
__device__ __forceinline__ void st_coh(int* p, int v) {
    __hip_atomic_store(p, v, __ATOMIC_RELAXED, __HIP_MEMORY_SCOPE_AGENT);
}
__device__ __forceinline__ int ld_coh(const int* p) {
    return __hip_atomic_load(p, __ATOMIC_RELAXED, __HIP_MEMORY_SCOPE_AGENT);
}

// rates fragment layout (units: shorts): [k>>5][m>>4][(k>>3)&3][m&15][k&7]
// Exactly the 16x16x32 MFMA A-fragment lane order (verified R1/R2/R5).
__device__ __forceinline__ int foff(int m, int k) {
    return ((k >> 5) << 10) | ((m >> 4) << 9) | (((k >> 3) & 3) << 7)
         | ((m & 15) << 3) | (k & 7);
}

// One-hop all-to-all grid barrier, 256B-padded flags, per-thread dedicated
// polling — R5 verbatim (best measured variant; R7 proved packed/coalesced
// polling regresses despite 10x less poll traffic) — EXCEPT the acquire
// fence is hoisted out (now conditional, once per 4 steps, in the caller).
// __syncthreads before arrival drains each wave's vmcnt, so flag visibility
// implies rates visibility at the coherence point.
__device__ __forceinline__ void grid_barrier(int* __restrict__ flags, int epoch) {
    __syncthreads();   // all waves: s_waitcnt vmcnt(0) — rates stores ordered
    if (threadIdx.x == 0)
        st_coh(&flags[(size_t)blockIdx.x * FSTR], epoch);
    while (ld_coh(&flags[(size_t)threadIdx.x * FSTR]) < epoch)
        __builtin_amdgcn_s_sleep(2);
    __syncthreads();
}

// Persistent kernel. One WG per CU; WG c owns output columns [16c,16c+16)
// for all 32 batches. W lives in registers as MFMA B-frags (128 VGPRs/wave)
// for the whole run. Per-neuron fp32 state (rec, rate, window-acc) in
// registers: thread owns elements (b = tid>>3, n = n0 + (tid&7)*2 + {0,1}).
__global__ __launch_bounds__(256, 1)
void rnn_kernel(const float* __restrict__ W,
                const float* __restrict__ ff,
                const float* __restrict__ rec0p,
                float* __restrict__ out,
                int* __restrict__ flags,
                short* __restrict__ ring)   // 4 x NB*NN bf16 ring
{
    const int tid  = threadIdx.x;
    const int wave = tid >> 6;
    const int lane = tid & 63;
    const int n0   = blockIdx.x * 16;

    __shared__ float part[4][32][18];   // per-wave K-partials (padded)

    // per-thread state element indices
    const int sb  = tid >> 3;           // batch 0..31
    const int nl0 = (tid & 7) * 2;      // even neuron-local index 0..14
    const int fo  = foff(sb, n0 + nl0); // fragment dword slot (even)

    // ---- init: rec0, rates0 = relu(ff[:,0] + rec0)
    const size_t sidx = (size_t)sb * NN + n0 + nl0;
    float rc0 = rec0p[sidx], rc1 = rec0p[sidx + 1];
    const float* ff0p = ff + ((size_t)sb * FF_T) * NN + n0 + nl0;
    float rt0 = fmaxf(ff0p[0] + rc0, 0.0f);
    float rt1 = fmaxf(ff0p[1] + rc1, 0.0f);
    float ac0 = 0.0f, ac1 = 0.0f;
    st_coh((int*)(ring + fo), (int)pack2bf(rt0, rt1));   // rates0 -> buf 0

    // ---- W (fp32 [k][n]) -> register bf16 B-fragments.
    // wave w covers k in [w*1024, (w+1)*1024); for K-step kt, lane holds
    // B[k = w*1024 + kt*32 + (lane>>4)*8 + j][n = n0 + (lane&15)], j=0..7
    short8 Bfr[32];
    {
        const int ncol  = n0 + (lane & 15);
        const size_t kb = (size_t)(wave * 1024 + ((lane >> 4) * 8));
        #pragma unroll
        for (int kt = 0; kt < 32; ++kt) {
            short8 f;
            #pragma unroll
            for (int j = 0; j < 8; ++j) {
                f[j] = f2bf(W[(kb + (size_t)kt * 32 + j) * NN + ncol]);
            }
            Bfr[kt] = f;
        }
    }

    int epoch = 1;
    grid_barrier(flags, epoch);   // rates0 globally visible

    // A-loads: contiguous fragment stream. Wave w owns shorts
    // [w*32768, (w+1)*32768) of a buffer; per kt two 1KB coalesced chunks
    // (m-tiles 0/1 at +0 / +512 shorts).
    const int wl = (wave << 15) + (lane << 3);

    for (int t = 0; t < TSTEPS; ++t) {
        // acquire fence once per ring cycle: invalidates L1/L2 so that
        // buffer t%4 (last cached at step t-4, rewritten at t-1 via sc1)
        // refills fresh from the coherence point. Placed AFTER the prior
        // barrier (writes complete) and BEFORE this step's reads.
        if ((t & 3) == 0)
            __builtin_amdgcn_fence(__ATOMIC_ACQUIRE, "agent");  // buffer_inv

        const short* __restrict__ rbuf = ring + (size_t)(t & 3) * RNG;
        short* __restrict__ wbuf       = ring + (size_t)((t + 1) & 3) * RNG;

        // this step's ff: issued at top of step, consumed after the MFMA
        // loop — HBM latency overlaps the MFMA chain
        const float* ffp = ff + ((size_t)sb * FF_T + t) * NN + n0 + nl0;
        const float ffv0 = ffp[0];
        const float ffv1 = ffp[1];

        f32x4 acc0 = {0.f, 0.f, 0.f, 0.f};
        f32x4 acc1 = {0.f, 0.f, 0.f, 0.f};
        const short* pw = rbuf + wl;
        #pragma unroll
        for (int kt = 0; kt < 32; ++kt) {
            short8 a0 = *(const short8*)(pw + (kt << 10));
            short8 a1 = *(const short8*)(pw + (kt << 10) + 512);
            acc0 = __builtin_amdgcn_mfma_f32_16x16x32_bf16(a0, Bfr[kt], acc0, 0, 0, 0);
            acc1 = __builtin_amdgcn_mfma_f32_16x16x32_bf16(a1, Bfr[kt], acc1, 0, 0, 0);
        }

        // C/D layout: col = lane&15, row = (lane>>4)*4 + reg  [m89-verified]
        const int prow = (lane >> 4) * 4;
        const int pcol = lane & 15;
        #pragma unroll
        for (int r = 0; r < 4; ++r) {
            part[wave][prow + r][pcol]      = acc0[r];
            part[wave][16 + prow + r][pcol] = acc1[r];
        }
        __syncthreads();

        // fused update on this thread's two elements (state in registers)
        const float h0 = part[0][sb][nl0] + part[1][sb][nl0]
                       + part[2][sb][nl0] + part[3][sb][nl0];
        const float h1 = part[0][sb][nl0+1] + part[1][sb][nl0+1]
                       + part[2][sb][nl0+1] + part[3][sb][nl0+1];
        rc0 = rc0 * 0.95122945f + h0 * 0.05f;   // exp(-dt/tau_syn), dt/tau_syn
        rc1 = rc1 * 0.95122945f + h1 * 0.05f;
        rt0 = rt0 * 0.90483743f + fmaxf(ffv0 + rc0, 0.0f) * 0.1f; // exp(-dt/tau), dt/tau
        rt1 = rt1 * 0.90483743f + fmaxf(ffv1 + rc1, 0.0f) * 0.1f;
        if (t >= 90) { ac0 += rt0; ac1 += rt1; }
        // publish new rates straight to the coherence point (sc1 store,
        // fragment layout — exactly one dword per thread)
        st_coh((int*)(wbuf + fo), (int)pack2bf(rt0, rt1));

        // record: windows end at t = 100,110,...,290 (first window = 11 terms
        // /10, matching cs[100]-cs[89] in the reference)
        if (t >= 100 && (t % 10) == 0) {
            const int w = (t - 100) / 10;
            float* op = out + ((size_t)sb * 20 + w) * NN + n0 + nl0;
            op[0] = ac0 * 0.1f;
            op[1] = ac1 * 0.1f;
            ac0 = 0.0f; ac1 = 0.0f;
        }

        epoch++;
        grid_barrier(flags, epoch);  // publishes new rates; orders ring reuse
    }
}

extern "C" void kernel_launch(void* const* d_in, const int* in_sizes, int n_in,
                              void* d_out, int out_size, void* d_ws, size_t ws_size,
                              hipStream_t stream)
{
    const float* W    = (const float*)d_in[0];   // Wab_T [4096,4096] fp32, row-major [k][n]
    const float* ff   = (const float*)d_in[1];   // [32,300,4096] fp32
    const float* rec0 = (const float*)d_in[2];   // [32,4096] fp32
    float* out = (float*)d_out;                  // [32,20,4096] fp32

    int*   flags = (int*)d_ws;                    // 256 flags, 256B apart (64KB)
    short* ring  = (short*)((char*)d_ws + 65536); // 4 x 256KB rates ring

    hipMemsetAsync(d_ws, 0, 65536, stream);       // graph-capturable memset node

    rnn_kernel<<<dim3(NBLK), dim3(256), 0, stream>>>(W, ff, rec0, out,
                                                     flags, ring);
}